// Round 2
// baseline (4561.822 us; speedup 1.0000x reference)
//
#include <hip/hip_runtime.h>

#define NN 50000
#define EE 800000
#define DD 128

// A = ndata @ Mw[0:128,:]  ;  B = ndata @ Mw[128:256,:] + Mb
__global__ __launch_bounds__(128) void prep_ab(
    const float* __restrict__ nd, const float* __restrict__ Mw,
    const float* __restrict__ Mb, float* __restrict__ A, float* __restrict__ B) {
  __shared__ float xs[8][128];
  const int c = threadIdx.x;
  const int row0 = blockIdx.x * 8;
  #pragma unroll
  for (int r = 0; r < 8; r++) {
    int n = row0 + r;
    xs[r][c] = (n < NN) ? nd[n * DD + c] : 0.f;
  }
  __syncthreads();
  float accA[8] = {0}, accB[8] = {0};
  for (int k = 0; k < 128; k += 4) {
    float w1[4], w2[4];
    #pragma unroll
    for (int j = 0; j < 4; j++) {
      w1[j] = Mw[(k + j) * DD + c];
      w2[j] = Mw[(128 + k + j) * DD + c];
    }
    #pragma unroll
    for (int r = 0; r < 8; r++) {
      float4 x = *(const float4*)&xs[r][k];
      accA[r] += x.x * w1[0] + x.y * w1[1] + x.z * w1[2] + x.w * w1[3];
      accB[r] += x.x * w2[0] + x.y * w2[1] + x.z * w2[2] + x.w * w2[3];
    }
  }
  float mb = Mb[c];
  #pragma unroll
  for (int r = 0; r < 8; r++) {
    int n = row0 + r;
    if (n < NN) { A[n * DD + c] = accA[r]; B[n * DD + c] = accB[r] + mb; }
  }
}

// S = A (self-loop), Xm = A (init of running max), deg = 1, bn sums = 0
__global__ __launch_bounds__(256) void init_agg(
    const float* __restrict__ A, float* __restrict__ S, float* __restrict__ Xm,
    float* __restrict__ deg, float* __restrict__ bns, float* __restrict__ bnq) {
  int i = blockIdx.x * 256 + threadIdx.x;
  if (i < NN * DD) { float a = A[i]; S[i] = a; Xm[i] = a; }
  if (i < NN) deg[i] = 1.f;
  if (i < DD) { bns[i] = 0.f; bnq[i] = 0.f; }
}

__device__ __forceinline__ void atomic_fmax(unsigned int* p, float v) {
  unsigned int b = __float_as_uint(v);
  if (!(b >> 31)) atomicMax((int*)p, (int)b);      // non-negative: int ordering == float ordering
  else            atomicMin(p, b);                  // negative: unsigned ordering reversed
}

// scatter A[src] into sum (S) and max (Xm) at dst; count degree
__global__ __launch_bounds__(256) void edge_scatter(
    const int* __restrict__ src, const int* __restrict__ dst,
    const float* __restrict__ A, float* __restrict__ S, float* __restrict__ Xm,
    float* __restrict__ deg) {
  int gid = blockIdx.x * 256 + threadIdx.x;
  int e = gid >> 5;
  if (e >= EE) return;
  int q = gid & 31;
  int s = src[e], d = dst[e];
  float4 av = ((const float4*)A)[s * 32 + q];
  float* Sp = S + d * DD + q * 4;
  atomicAdd(Sp + 0, av.x);
  atomicAdd(Sp + 1, av.y);
  atomicAdd(Sp + 2, av.z);
  atomicAdd(Sp + 3, av.w);
  unsigned int* Xp = (unsigned int*)Xm + d * DD + q * 4;
  atomic_fmax(Xp + 0, av.x);
  atomic_fmax(Xp + 1, av.y);
  atomic_fmax(Xp + 2, av.z);
  atomic_fmax(Xp + 3, av.w);
  if (q == 0) atomicAdd(deg + d, 1.f);
}

// S -> mean = S/deg + B ; Xm -> max + B ; amp = log(deg+1)/2.5
__global__ __launch_bounds__(256) void node_prep(
    const float* __restrict__ Bv, float* __restrict__ S, float* __restrict__ Xm,
    const float* __restrict__ deg, float* __restrict__ amp) {
  int i = blockIdx.x * 256 + threadIdx.x;
  if (i >= NN * DD) return;
  int n = i >> 7;
  float dg = deg[n];
  float b = Bv[i];
  S[i] = S[i] / dg + b;
  Xm[i] = Xm[i] + b;
  if ((i & 127) == 0) amp[n] = logf(dg + 1.f) * (1.f / 2.5f);
}

// H = nd@W0 + mean@(W1+W3) + max@W2 + amp*mean@(W4+W6) + amp*max@W5 + Ub
__global__ __launch_bounds__(128) void u_matmul(
    const float* __restrict__ nd, const float* __restrict__ S,
    const float* __restrict__ Xm, const float* __restrict__ amp,
    const float* __restrict__ Uw, const float* __restrict__ Ub,
    float* __restrict__ H) {
  __shared__ float xs[16][128];
  const int c = threadIdx.x;
  const int row0 = blockIdx.x * 16;
  float acc[16];
  #pragma unroll
  for (int r = 0; r < 16; r++) acc[r] = 0.f;

  for (int p = 0; p < 5; p++) {
    __syncthreads();
    #pragma unroll
    for (int r = 0; r < 16; r++) {
      int n = row0 + r;
      float v = 0.f;
      if (n < NN) {
        int idx = n * DD + c;
        switch (p) {
          case 0: v = nd[idx]; break;
          case 1: v = S[idx]; break;
          case 2: v = Xm[idx]; break;
          case 3: v = S[idx] * amp[n]; break;
          case 4: v = Xm[idx] * amp[n]; break;
        }
      }
      xs[r][c] = v;
    }
    __syncthreads();
    for (int k = 0; k < 128; k += 4) {
      float w[4];
      #pragma unroll
      for (int j = 0; j < 4; j++) {
        int kk = k + j;
        float wv;
        switch (p) {
          case 0: wv = Uw[kk * DD + c]; break;
          case 1: wv = Uw[(128 + kk) * DD + c] + Uw[(384 + kk) * DD + c]; break;
          case 2: wv = Uw[(256 + kk) * DD + c]; break;
          case 3: wv = Uw[(512 + kk) * DD + c] + Uw[(768 + kk) * DD + c]; break;
          default: wv = Uw[(640 + kk) * DD + c]; break;
        }
        w[j] = wv;
      }
      #pragma unroll
      for (int r = 0; r < 16; r++) {
        float4 x = *(const float4*)&xs[r][k];
        acc[r] += x.x * w[0] + x.y * w[1] + x.z * w[2] + x.w * w[3];
      }
    }
  }
  float ub = Ub[c];
  #pragma unroll
  for (int r = 0; r < 16; r++) {
    int n = row0 + r;
    if (n < NN) H[n * DD + c] = acc[r] + ub;
  }
}

__global__ __launch_bounds__(256) void bn_stats(
    const float* __restrict__ H, float* __restrict__ bns, float* __restrict__ bnq) {
  int c = threadIdx.x & 127, g = threadIdx.x >> 7;
  float s = 0.f, q = 0.f;
  for (int n = blockIdx.x * 2 + g; n < NN; n += gridDim.x * 2) {
    float v = H[n * DD + c];
    s += v; q += v * v;
  }
  atomicAdd(bns + c, s);
  atomicAdd(bnq + c, q);
}

__global__ __launch_bounds__(128) void final_k(
    const float* __restrict__ H, const float* __restrict__ bns, const float* __restrict__ bnq,
    const float* __restrict__ gamma, const float* __restrict__ beta,
    const float* __restrict__ mw, const float* __restrict__ mb,
    float* __restrict__ out) {
  __shared__ float xs[16][128];
  const int c = threadIdx.x;
  const int row0 = blockIdx.x * 16;
  float mu = bns[c] * (1.f / NN);
  float var = bnq[c] * (1.f / NN) - mu * mu;
  float a = gamma[c] * rsqrtf(var + 1e-5f);
  float bc = beta[c] - mu * a;
  #pragma unroll
  for (int r = 0; r < 16; r++) {
    int n = row0 + r;
    xs[r][c] = (n < NN) ? a * H[n * DD + c] + bc : 0.f;
  }
  __syncthreads();
  float acc[16];
  #pragma unroll
  for (int r = 0; r < 16; r++) acc[r] = 0.f;
  for (int k = 0; k < 128; k += 4) {
    float w[4];
    #pragma unroll
    for (int j = 0; j < 4; j++) w[j] = mw[(k + j) * DD + c];
    #pragma unroll
    for (int r = 0; r < 16; r++) {
      float4 x = *(const float4*)&xs[r][k];
      acc[r] += x.x * w[0] + x.y * w[1] + x.z * w[2] + x.w * w[3];
    }
  }
  float mbv = mb[c];
  #pragma unroll
  for (int r = 0; r < 16; r++) {
    int n = row0 + r;
    if (n < NN) {
      float o = acc[r] + mbv;
      o = o > 0.f ? o : 0.01f * o;
      out[n * DD + c] = o;
    }
  }
}

extern "C" void kernel_launch(void* const* d_in, const int* in_sizes, int n_in,
                              void* d_out, int out_size, void* d_ws, size_t ws_size,
                              hipStream_t stream) {
  const float* nd    = (const float*)d_in[0];
  const float* Mw    = (const float*)d_in[1];
  const float* Mb    = (const float*)d_in[2];
  const float* Uw    = (const float*)d_in[3];
  const float* Ub    = (const float*)d_in[4];
  const float* gamma = (const float*)d_in[5];
  const float* beta  = (const float*)d_in[6];
  const float* mixw  = (const float*)d_in[7];
  const float* mixb  = (const float*)d_in[8];
  const int* src = (const int*)d_in[9];
  const int* dst = (const int*)d_in[10];
  float* out = (float*)d_out;

  float* ws  = (float*)d_ws;
  float* A   = ws;
  float* Bv  = A + NN * DD;
  float* S   = Bv + NN * DD;
  float* Xm  = S + NN * DD;
  float* H   = Xm + NN * DD;
  float* deg = H + NN * DD;
  float* amp = deg + NN;
  float* bns = amp + NN;
  float* bnq = bns + DD;

  prep_ab<<<(NN + 7) / 8, 128, 0, stream>>>(nd, Mw, Mb, A, Bv);
  init_agg<<<(NN * DD + 255) / 256, 256, 0, stream>>>(A, S, Xm, deg, bns, bnq);
  edge_scatter<<<(EE * 32 + 255) / 256, 256, 0, stream>>>(src, dst, A, S, Xm, deg);
  node_prep<<<(NN * DD + 255) / 256, 256, 0, stream>>>(Bv, S, Xm, deg, amp);
  u_matmul<<<(NN + 15) / 16, 128, 0, stream>>>(nd, S, Xm, amp, Uw, Ub, H);
  bn_stats<<<500, 256, 0, stream>>>(H, bns, bnq);
  final_k<<<(NN + 15) / 16, 128, 0, stream>>>(H, bns, bnq, gamma, beta, mixw, mixb, out);
}

// Round 3
// 878.126 us; speedup vs baseline: 5.1950x; 5.1950x over previous
//
#include <hip/hip_runtime.h>

#define NN 50000
#define EE 800000
#define DD 128

// A = ndata @ Mw[0:128,:]  ;  B = ndata @ Mw[128:256,:] + Mb
__global__ __launch_bounds__(128) void prep_ab(
    const float* __restrict__ nd, const float* __restrict__ Mw,
    const float* __restrict__ Mb, float* __restrict__ A, float* __restrict__ B) {
  __shared__ float xs[8][128];
  const int c = threadIdx.x;
  const int row0 = blockIdx.x * 8;
  #pragma unroll
  for (int r = 0; r < 8; r++) {
    int n = row0 + r;
    xs[r][c] = (n < NN) ? nd[n * DD + c] : 0.f;
  }
  __syncthreads();
  float accA[8] = {0}, accB[8] = {0};
  for (int k = 0; k < 128; k += 4) {
    float w1[4], w2[4];
    #pragma unroll
    for (int j = 0; j < 4; j++) {
      w1[j] = Mw[(k + j) * DD + c];
      w2[j] = Mw[(128 + k + j) * DD + c];
    }
    #pragma unroll
    for (int r = 0; r < 8; r++) {
      float4 x = *(const float4*)&xs[r][k];
      accA[r] += x.x * w1[0] + x.y * w1[1] + x.z * w1[2] + x.w * w1[3];
      accB[r] += x.x * w2[0] + x.y * w2[1] + x.z * w2[2] + x.w * w2[3];
    }
  }
  float mb = Mb[c];
  #pragma unroll
  for (int r = 0; r < 8; r++) {
    int n = row0 + r;
    if (n < NN) { A[n * DD + c] = accA[r]; B[n * DD + c] = accB[r] + mb; }
  }
}

__global__ __launch_bounds__(256) void init_small(
    unsigned int* __restrict__ cnt, float* __restrict__ bns, float* __restrict__ bnq) {
  int i = blockIdx.x * 256 + threadIdx.x;
  if (i < NN) cnt[i] = 0u;
  if (i < DD) { bns[i] = 0.f; bnq[i] = 0.f; }
}

__global__ __launch_bounds__(256) void deg_count(
    const int* __restrict__ dst, unsigned int* __restrict__ cnt) {
  int e = blockIdx.x * 256 + threadIdx.x;
  if (e < EE) atomicAdd(&cnt[dst[e]], 1u);
}

// single-workgroup exclusive scan of cnt[NN] -> off, cursor
__global__ __launch_bounds__(1024) void scan_k(
    const unsigned int* __restrict__ cnt, unsigned int* __restrict__ off,
    unsigned int* __restrict__ cursor) {
  __shared__ unsigned int part[1024];
  const int t = threadIdx.x;
  const int CH = (NN + 1023) / 1024;  // 49
  int beg = t * CH, end = beg + CH;
  if (end > NN) end = NN;
  unsigned int s = 0;
  for (int i = beg; i < end; i++) s += cnt[i];
  part[t] = s;
  __syncthreads();
  for (int d = 1; d < 1024; d <<= 1) {
    unsigned int v = (t >= d) ? part[t - d] : 0u;
    __syncthreads();
    part[t] += v;
    __syncthreads();
  }
  unsigned int run = part[t] - s;  // exclusive prefix of chunk
  for (int i = beg; i < end; i++) {
    off[i] = run; cursor[i] = run; run += cnt[i];
  }
  if (t == 0) off[NN] = EE;
}

__global__ __launch_bounds__(256) void fill_k(
    const int* __restrict__ src, const int* __restrict__ dst,
    unsigned int* __restrict__ cursor, unsigned int* __restrict__ eidx) {
  int e = blockIdx.x * 256 + threadIdx.x;
  if (e < EE) {
    unsigned int p = atomicAdd(&cursor[dst[e]], 1u);
    eidx[p] = (unsigned int)src[e];
  }
}

// gather-aggregate: one wave per node. sum/max of A[src] rows (+ self loop),
// then S = sum/deg + B ; Xm = max + B ; amp = log(deg+1)/2.5
__global__ __launch_bounds__(256) void aggregate(
    const float* __restrict__ A, const float* __restrict__ Bv,
    const unsigned int* __restrict__ off, const unsigned int* __restrict__ eidx,
    float* __restrict__ S, float* __restrict__ Xm, float* __restrict__ amp) {
  int wave = threadIdx.x >> 6, lane = threadIdx.x & 63;
  int n = blockIdx.x * 4 + wave;
  if (n >= NN) return;
  unsigned int b0 = off[n], b1 = off[n + 1];
  float2 sum = ((const float2*)(A + (size_t)n * DD))[lane];
  float2 mx = sum;
  for (unsigned int j0 = b0; j0 < b1; j0 += 64) {
    int m = (int)min(64u, b1 - j0);
    int myi = (lane < m) ? (int)eidx[j0 + lane] : 0;
    for (int j = 0; j < m; j++) {
      int sN = __shfl(myi, j);
      float2 a = ((const float2*)(A + (size_t)sN * DD))[lane];
      sum.x += a.x; sum.y += a.y;
      mx.x = fmaxf(mx.x, a.x); mx.y = fmaxf(mx.y, a.y);
    }
  }
  float degf = (float)(b1 - b0) + 1.f;
  float inv = 1.f / degf;
  float2 b = ((const float2*)(Bv + (size_t)n * DD))[lane];
  float2 sm = {sum.x * inv + b.x, sum.y * inv + b.y};
  float2 xm = {mx.x + b.x, mx.y + b.y};
  ((float2*)(S + (size_t)n * DD))[lane] = sm;
  ((float2*)(Xm + (size_t)n * DD))[lane] = xm;
  if (lane == 0) amp[n] = logf(degf + 1.f) * 0.4f;
}

// H = nd@W0 + S@(W1+W3) + amp*S@(W4+W6) + Xm@W2 + amp*Xm@W5 + Ub
__global__ __launch_bounds__(128) void u_matmul(
    const float* __restrict__ nd, const float* __restrict__ S,
    const float* __restrict__ Xm, const float* __restrict__ amp,
    const float* __restrict__ Uw, const float* __restrict__ Ub,
    float* __restrict__ H) {
  __shared__ float xs[16][128];
  const int c = threadIdx.x;
  const int row0 = blockIdx.x * 16;
  float acc[16];
  float ampv[16];
  #pragma unroll
  for (int r = 0; r < 16; r++) {
    acc[r] = 0.f;
    int n = row0 + r;
    ampv[r] = (n < NN) ? amp[n] : 0.f;
  }

  for (int p = 0; p < 3; p++) {
    __syncthreads();
    #pragma unroll
    for (int r = 0; r < 16; r++) {
      int n = row0 + r;
      float v = 0.f;
      if (n < NN) {
        int idx = n * DD + c;
        v = (p == 0) ? nd[idx] : (p == 1) ? S[idx] : Xm[idx];
      }
      xs[r][c] = v;
    }
    __syncthreads();
    if (p == 0) {
      for (int k = 0; k < 128; k += 4) {
        float w[4];
        #pragma unroll
        for (int j = 0; j < 4; j++) w[j] = Uw[(k + j) * DD + c];
        #pragma unroll
        for (int r = 0; r < 16; r++) {
          float4 x = *(const float4*)&xs[r][k];
          acc[r] += x.x * w[0] + x.y * w[1] + x.z * w[2] + x.w * w[3];
        }
      }
    } else {
      float acc2[16];
      #pragma unroll
      for (int r = 0; r < 16; r++) acc2[r] = 0.f;
      const int ia = (p == 1) ? 128 : 256;   // identity panel row offset
      const int ib = (p == 1) ? 384 : -1;    // second identity panel (mean dup)
      const int aa = (p == 1) ? 512 : 640;   // amplification panel
      const int ab = (p == 1) ? 768 : -1;
      for (int k = 0; k < 128; k += 4) {
        float wi[4], wa[4];
        #pragma unroll
        for (int j = 0; j < 4; j++) {
          int kk = k + j;
          float w1 = Uw[(ia + kk) * DD + c];
          float w2 = Uw[(aa + kk) * DD + c];
          if (ib >= 0) { w1 += Uw[(ib + kk) * DD + c]; w2 += Uw[(ab + kk) * DD + c]; }
          wi[j] = w1; wa[j] = w2;
        }
        #pragma unroll
        for (int r = 0; r < 16; r++) {
          float4 x = *(const float4*)&xs[r][k];
          acc[r]  += x.x * wi[0] + x.y * wi[1] + x.z * wi[2] + x.w * wi[3];
          acc2[r] += x.x * wa[0] + x.y * wa[1] + x.z * wa[2] + x.w * wa[3];
        }
      }
      #pragma unroll
      for (int r = 0; r < 16; r++) acc[r] += ampv[r] * acc2[r];
    }
  }
  float ub = Ub[c];
  #pragma unroll
  for (int r = 0; r < 16; r++) {
    int n = row0 + r;
    if (n < NN) H[n * DD + c] = acc[r] + ub;
  }
}

__global__ __launch_bounds__(256) void bn_stats(
    const float* __restrict__ H, float* __restrict__ bns, float* __restrict__ bnq) {
  int c = threadIdx.x & 127, g = threadIdx.x >> 7;
  float s = 0.f, q = 0.f;
  for (int n = blockIdx.x * 2 + g; n < NN; n += gridDim.x * 2) {
    float v = H[n * DD + c];
    s += v; q += v * v;
  }
  atomicAdd(bns + c, s);
  atomicAdd(bnq + c, q);
}

__global__ __launch_bounds__(128) void final_k(
    const float* __restrict__ H, const float* __restrict__ bns, const float* __restrict__ bnq,
    const float* __restrict__ gamma, const float* __restrict__ beta,
    const float* __restrict__ mw, const float* __restrict__ mb,
    float* __restrict__ out) {
  __shared__ float xs[16][128];
  const int c = threadIdx.x;
  const int row0 = blockIdx.x * 16;
  float mu = bns[c] * (1.f / NN);
  float var = bnq[c] * (1.f / NN) - mu * mu;
  float a = gamma[c] * rsqrtf(var + 1e-5f);
  float bc = beta[c] - mu * a;
  #pragma unroll
  for (int r = 0; r < 16; r++) {
    int n = row0 + r;
    xs[r][c] = (n < NN) ? a * H[n * DD + c] + bc : 0.f;
  }
  __syncthreads();
  float acc[16];
  #pragma unroll
  for (int r = 0; r < 16; r++) acc[r] = 0.f;
  for (int k = 0; k < 128; k += 4) {
    float w[4];
    #pragma unroll
    for (int j = 0; j < 4; j++) w[j] = mw[(k + j) * DD + c];
    #pragma unroll
    for (int r = 0; r < 16; r++) {
      float4 x = *(const float4*)&xs[r][k];
      acc[r] += x.x * w[0] + x.y * w[1] + x.z * w[2] + x.w * w[3];
    }
  }
  float mbv = mb[c];
  #pragma unroll
  for (int r = 0; r < 16; r++) {
    int n = row0 + r;
    if (n < NN) {
      float o = acc[r] + mbv;
      o = o > 0.f ? o : 0.01f * o;
      out[n * DD + c] = o;
    }
  }
}

extern "C" void kernel_launch(void* const* d_in, const int* in_sizes, int n_in,
                              void* d_out, int out_size, void* d_ws, size_t ws_size,
                              hipStream_t stream) {
  const float* nd    = (const float*)d_in[0];
  const float* Mw    = (const float*)d_in[1];
  const float* Mb    = (const float*)d_in[2];
  const float* Uw    = (const float*)d_in[3];
  const float* Ub    = (const float*)d_in[4];
  const float* gamma = (const float*)d_in[5];
  const float* beta  = (const float*)d_in[6];
  const float* mixw  = (const float*)d_in[7];
  const float* mixb  = (const float*)d_in[8];
  const int* src = (const int*)d_in[9];
  const int* dst = (const int*)d_in[10];
  float* out = (float*)d_out;

  float* ws  = (float*)d_ws;
  float* A   = ws;
  float* Bv  = A + NN * DD;
  float* S   = Bv + NN * DD;
  float* Xm  = S + NN * DD;
  float* H   = Xm + NN * DD;
  float* amp = H + NN * DD;
  float* bns = amp + NN;
  float* bnq = bns + DD;
  unsigned int* cnt    = (unsigned int*)(bnq + DD);
  unsigned int* off    = cnt + NN;
  unsigned int* cursor = off + NN + 1;
  unsigned int* eidx   = cursor + NN;

  prep_ab<<<(NN + 7) / 8, 128, 0, stream>>>(nd, Mw, Mb, A, Bv);
  init_small<<<(NN + 255) / 256, 256, 0, stream>>>(cnt, bns, bnq);
  deg_count<<<(EE + 255) / 256, 256, 0, stream>>>(dst, cnt);
  scan_k<<<1, 1024, 0, stream>>>(cnt, off, cursor);
  fill_k<<<(EE + 255) / 256, 256, 0, stream>>>(src, dst, cursor, eidx);
  aggregate<<<(NN + 3) / 4, 256, 0, stream>>>(A, Bv, off, eidx, S, Xm, amp);
  u_matmul<<<(NN + 15) / 16, 128, 0, stream>>>(nd, S, Xm, amp, Uw, Ub, H);
  bn_stats<<<500, 256, 0, stream>>>(H, bns, bnq);
  final_k<<<(NN + 15) / 16, 128, 0, stream>>>(H, bns, bnq, gamma, beta, mixw, mixb, out);
}